// Round 4
// baseline (72.707 us; speedup 1.0000x reference)
//
#include <hip/hip_runtime.h>
#include <math.h>

#define BB 2048
#define T  200
#define H  64
#define H1 80
#define H2 40

#define MT   13            // 16-row M tiles (208 padded rows)
#define TPAD 208
#define SB2_STRIDE 104     // ushort/row W2^T in ws
#define SCR_STRIDE 104     // ushort/row per-wave hid scratch (208 B = 13*16)

typedef __attribute__((ext_vector_type(8))) short short8;
typedef __attribute__((ext_vector_type(4))) float floatx4;

// ws layout (float words):
#define WS_WKT 0                       // [80][64] f32: W1k - W1qk  ([f][h])
#define WS_WPT (WS_WKT + H1 * H)       // [80][64] f32: W1qk       ([f][h])
#define WS_WQ  (WS_WPT + H1 * H)       // [64][80] f32: W1q + W1qk ([h][f])
#define WS_W2T (WS_WQ + H * H1)        // [48][104] bf16 (ushort), zero-padded

__device__ __forceinline__ unsigned short f2b(float x) {
    union { float f; unsigned u; } v; v.f = x;
    unsigned r = v.u + 0x7FFF + ((v.u >> 16) & 1);   // RNE (finite inputs only)
    return (unsigned short)(r >> 16);
}
__device__ __forceinline__ float b2f(unsigned short u) {
    union { unsigned u; float f; } v; v.u = ((unsigned)u) << 16;
    return v.f;
}

// ---------------- prep: fold W1, transpose/convert W2 ----------------
__global__ void prep_kernel(const float* __restrict__ W1,
                            const float* __restrict__ W2,
                            float* __restrict__ ws) {
    int i = blockIdx.x * 256 + threadIdx.x;          // 0..5119
    if (i < H1 * H) {
        int f = i / H, h = i % H;
        // din = [q, k, q-k, q*k]; W1 rows: [0:64)q [64:128)k [128:192)q-k [192:256)q*k
        ws[WS_WKT + i] = W1[(64 + h) * H1 + f] - W1[(128 + h) * H1 + f];
        ws[WS_WPT + i] = W1[(192 + h) * H1 + f];
        ws[WS_WQ + h * H1 + f] = W1[h * H1 + f] + W1[(128 + h) * H1 + f];
    }
    if (i < 48 * SB2_STRIDE) {                       // 4992 bf16 elems
        int n = i / SB2_STRIDE, k = i % SB2_STRIDE;
        float v = (n < H2 && k < H1) ? W2[k * H2 + n] : 0.f;
        ((unsigned short*)(ws + WS_W2T))[i] = f2b(v);
    }
}

// ---------------- main: one block (512 thr) per batch row ----------------
__global__ __launch_bounds__(512, 6)
void din_attn_kernel(const float* __restrict__ query,
                     const float* __restrict__ keys,
                     const int*   __restrict__ keys_length,
                     const float* __restrict__ b1,
                     const float* __restrict__ b2,
                     const float* __restrict__ Wfc,
                     const float* __restrict__ bfc,
                     const float* __restrict__ ws,
                     float* __restrict__ out)
{
    // sA: swizzled bf16 keys [208 rows x 64 cols, 128B rows]; after the
    // af-hoist barrier the same 26624B become 8 per-wave hid scratch bufs.
    __shared__ unsigned short sA[TPAD * 64];     // 26624 B
    __shared__ unsigned short sB1[H1 * 64];      // 10240 B swizzled; sOut aliases later
    __shared__ float sQh[H1];                    //   320 B
    __shared__ float sS[TPAD];                   //   832 B
    __shared__ float sRed[16];                   //    64 B

    const int b   = blockIdx.x;
    const int tid = threadIdx.x;
    const int wv  = tid >> 6, ln = tid & 63;
    const int lrow = ln & 15;             // m/n index within a 16-tile
    const int lk8  = (ln >> 4) * 8;       // k-element offset of this lane's frag
    const int sw   = (lrow & 7) << 3;     // frag-read swizzle (row&7 == lrow&7)

    const float* kb = keys + (size_t)b * T * H;
    const float* qg = query + (size_t)b * H;
    const unsigned short* w2t = (const unsigned short*)(ws + WS_W2T);

    // ---- hoisted small loads ----
    float wfcv[3], b2v[3];
    #pragma unroll
    for (int nt = 0; nt < 3; ++nt) {
        int g = nt * 16 + lrow;
        wfcv[nt] = (g < H2) ? Wfc[g] : 0.f;
        b2v[nt]  = (g < H2) ? b2[g]  : 0.f;
    }
    float bfc0 = bfc[0];
    int len = keys_length[b];

    // ===== phase 0: stage keys (6-7 loads in flight), fold W1, qh =====
    const float4* kb4 = reinterpret_cast<const float4*>(kb);
    float4 kv[6];
    #pragma unroll
    for (int k = 0; k < 6; ++k) kv[k] = kb4[tid + (k << 9)];
    const bool tail = tid < (T * H / 4 - 3072);     // 128 threads
    float4 kvt;
    if (tail) kvt = kb4[tid + 3072];

    #pragma unroll
    for (int k = 0; k < 6; ++k) {
        int idx = tid + (k << 9);
        int t = idx >> 4, h = (idx & 15) << 2;
        uint2 p;
        p.x = (unsigned)f2b(kv[k].x) | ((unsigned)f2b(kv[k].y) << 16);
        p.y = (unsigned)f2b(kv[k].z) | ((unsigned)f2b(kv[k].w) << 16);
        *reinterpret_cast<uint2*>(&sA[t * 64 + (h ^ ((t & 7) << 3))]) = p;
    }
    if (tail) {
        int idx = tid + 3072;
        int t = idx >> 4, h = (idx & 15) << 2;
        uint2 p;
        p.x = (unsigned)f2b(kvt.x) | ((unsigned)f2b(kvt.y) << 16);
        p.y = (unsigned)f2b(kvt.z) | ((unsigned)f2b(kvt.w) << 16);
        *reinterpret_cast<uint2*>(&sA[t * 64 + (h ^ ((t & 7) << 3))]) = p;
    }
    if (tid < 64) {                                  // zero pad rows 200..207
        uint4 z; z.x = z.y = z.z = z.w = 0;
        reinterpret_cast<uint4*>(&sA[200 * 64])[tid] = z;
    }
    // fold q into stage-1 weights: B1[f][h] = Wk[f][h] + q[h]*Wp[f][h]
    #pragma unroll
    for (int k = 0; k < 5; ++k) {
        int idx = tid + (k << 9);                    // 0..2559
        int f = idx >> 5, hp = (idx & 31) << 1;
        float q0 = qg[hp], q1 = qg[hp + 1];
        float v0 = ws[WS_WKT + f * H + hp]     + q0 * ws[WS_WPT + f * H + hp];
        float v1 = ws[WS_WKT + f * H + hp + 1] + q1 * ws[WS_WPT + f * H + hp + 1];
        unsigned p = (unsigned)f2b(v0) | ((unsigned)f2b(v1) << 16);
        *reinterpret_cast<unsigned*>(&sB1[f * 64 + (hp ^ ((f & 7) << 3))]) = p;
    }
    if (tid < H1) {
        float acc = b1[tid];
        #pragma unroll 8
        for (int h = 0; h < H; ++h) acc += qg[h] * ws[WS_WQ + h * H1 + tid];
        sQh[tid] = acc;
    }
    __syncthreads();

    // ===== phase 0.5: hoist key A-fragments, then keys-LDS is dead =====
    short8 af[2][2];
    bool has[2];
    #pragma unroll
    for (int mi = 0; mi < 2; ++mi) {
        int mt = wv + mi * 8;
        has[mi] = (mt < MT);
        if (has[mi]) {
            #pragma unroll
            for (int ks = 0; ks < 2; ++ks) {
                int row = mt * 16 + lrow;
                af[mi][ks] = *reinterpret_cast<const short8*>(
                    &sA[row * 64 + ((ks * 32 + lk8) ^ sw)]);
            }
        }
    }
    __syncthreads();   // all af reads complete before scratch overwrites sA

    // per-wave hid scratch inside sA; zero cols 80..95 (K=96 zero-pad)
    unsigned short* scr = &sA[wv * 16 * SCR_STRIDE];
    {
        uint2 z; z.x = 0; z.y = 0;
        *reinterpret_cast<uint2*>(&scr[(ln >> 2) * SCR_STRIDE + 80 + (ln & 3) * 4]) = z;
    }

    // ===== phase 1: per-M-tile stage1 MFMA -> scratch -> stage2 MFMA =====
    #pragma unroll
    for (int mi = 0; mi < 2; ++mi) {
        if (!has[mi]) break;
        int mt = wv + mi * 8;
        // stage-1: hid[16][80] = ReLU(A @ B1 + qh); B1 streamed from LDS
        #pragma unroll
        for (int nt = 0; nt < 5; ++nt) {
            int row = nt * 16 + lrow;
            short8 bf0 = *reinterpret_cast<const short8*>(&sB1[row * 64 + (lk8 ^ sw)]);
            short8 bf1 = *reinterpret_cast<const short8*>(&sB1[row * 64 + ((32 + lk8) ^ sw)]);
            floatx4 acc = {0.f, 0.f, 0.f, 0.f};
            acc = __builtin_amdgcn_mfma_f32_16x16x32_bf16(af[mi][0], bf0, acc, 0, 0, 0);
            acc = __builtin_amdgcn_mfma_f32_16x16x32_bf16(af[mi][1], bf1, acc, 0, 0, 0);
            float qh = sQh[nt * 16 + lrow];   // D: col=lane&15 (f), row=(lane>>4)*4+r (t)
            int rb = (ln >> 4) * 4;
            #pragma unroll
            for (int r = 0; r < 4; ++r)
                scr[(rb + r) * SCR_STRIDE + nt * 16 + lrow] = f2b(fmaxf(acc[r] + qh, 0.f));
        }
        // stage-2: scores = relu(hid @ W2 + b2) . Wfc  (own scratch, no barrier)
        short8 a2[3];
        #pragma unroll
        for (int ks = 0; ks < 3; ++ks)
            a2[ks] = *reinterpret_cast<const short8*>(
                &scr[lrow * SCR_STRIDE + ks * 32 + lk8]);
        floatx4 vsum = {0.f, 0.f, 0.f, 0.f};
        #pragma unroll
        for (int nt = 0; nt < 3; ++nt) {
            floatx4 acc = {0.f, 0.f, 0.f, 0.f};
            #pragma unroll
            for (int ks = 0; ks < 3; ++ks) {
                short8 b2frag = *reinterpret_cast<const short8*>(
                    &w2t[(nt * 16 + lrow) * SB2_STRIDE + ks * 32 + lk8]);
                acc = __builtin_amdgcn_mfma_f32_16x16x32_bf16(a2[ks], b2frag, acc, 0, 0, 0);
            }
            #pragma unroll
            for (int r = 0; r < 4; ++r)
                vsum[r] += fmaxf(acc[r] + b2v[nt], 0.f) * wfcv[nt];
        }
        #pragma unroll
        for (int r = 0; r < 4; ++r) {
            vsum[r] += __shfl_xor(vsum[r], 1);
            vsum[r] += __shfl_xor(vsum[r], 2);
            vsum[r] += __shfl_xor(vsum[r], 4);
            vsum[r] += __shfl_xor(vsum[r], 8);
        }
        if (lrow == 0) {
            int tb = mt * 16 + (ln >> 4) * 4;
            #pragma unroll
            for (int r = 0; r < 4; ++r)
                sS[tb + r] = (vsum[r] + bfc0) * 0.125f;
        }
    }
    __syncthreads();

    // ===== phase 2: masked softmax over t =====
    float s = -INFINITY;
    if (tid < TPAD) s = (tid < len) ? sS[tid] : -INFINITY;
    float m = s;
    #pragma unroll
    for (int off = 32; off > 0; off >>= 1) m = fmaxf(m, __shfl_xor(m, off));
    if (ln == 0) sRed[wv] = m;
    __syncthreads();
    float mx = sRed[0];
    #pragma unroll
    for (int i = 1; i < 8; ++i) mx = fmaxf(mx, sRed[i]);
    float e = (tid < TPAD) ? __expf(s - mx) : 0.f;
    float sum = e;
    #pragma unroll
    for (int off = 32; off > 0; off >>= 1) sum += __shfl_xor(sum, off);
    if (ln == 0) sRed[8 + wv] = sum;
    __syncthreads();
    float denom = sRed[8];
    #pragma unroll
    for (int i = 1; i < 8; ++i) denom += sRed[8 + i];
    float inv = 1.f / denom;
    if (tid < TPAD) sS[tid] = e * inv;
    __syncthreads();

    // ===== phase 3: out[b][h] = sum_t attn[t] * keys[t][h]  (keys from L2/L3) =====
    float* sOut = reinterpret_cast<float*>(sB1);   // sB1 dead after phase 1
    float acc = 0.f;
    int t0 = wv * 26;
    int tend = t0 + 26 < T ? t0 + 26 : T;
    for (int t = t0; t < tend; ++t)
        acc += sS[t] * kb[t * H + ln];
    sOut[wv * 64 + ln] = acc;
    __syncthreads();
    if (tid < H) {
        float o = 0.f;
        #pragma unroll
        for (int g = 0; g < 8; ++g) o += sOut[g * 64 + tid];
        out[(size_t)b * H + tid] = o;
    }
}

extern "C" void kernel_launch(void* const* d_in, const int* in_sizes, int n_in,
                              void* d_out, int out_size, void* d_ws, size_t ws_size,
                              hipStream_t stream) {
    const float* query       = (const float*)d_in[0];
    const float* keys        = (const float*)d_in[1];
    const int*   keys_length = (const int*)  d_in[2];
    const float* W1          = (const float*)d_in[3];
    const float* b1          = (const float*)d_in[4];
    const float* W2          = (const float*)d_in[5];
    const float* b2          = (const float*)d_in[6];
    const float* Wfc         = (const float*)d_in[7];
    const float* bfc         = (const float*)d_in[8];
    float* out = (float*)d_out;
    float* ws  = (float*)d_ws;

    prep_kernel<<<20, 256, 0, stream>>>(W1, W2, ws);
    din_attn_kernel<<<BB, 512, 0, stream>>>(query, keys, keys_length,
                                            b1, b2, Wfc, bfc, ws, out);
}

// Round 5
// 60.934 us; speedup vs baseline: 1.1932x; 1.1932x over previous
//
#include <hip/hip_runtime.h>
#include <math.h>

#define BB 2048
#define T  200
#define H  64
#define H1 80
#define H2 40

#define MT   13            // 16-row M tiles (208 padded rows)
#define TPAD 208
#define SB2_STRIDE 104     // ushort/row W2^T in ws
#define SCR_STRIDE 104     // ushort/row per-wave hid scratch (208 B = 13*16)

typedef __attribute__((ext_vector_type(8))) short short8;
typedef __attribute__((ext_vector_type(4))) float floatx4;

// ws layout (float words):
#define WS_WKT 0                       // [80][64] f32: W1k - W1qk  ([f][h])
#define WS_WPT (WS_WKT + H1 * H)       // [80][64] f32: W1qk       ([f][h])
#define WS_WQ  (WS_WPT + H1 * H)       // [64][80] f32: W1q + W1qk ([h][f])
#define WS_W2T (WS_WQ + H * H1)        // [48][104] bf16 (ushort), zero-padded

__device__ __forceinline__ unsigned short f2b(float x) {
    union { float f; unsigned u; } v; v.f = x;
    unsigned r = v.u + 0x7FFF + ((v.u >> 16) & 1);   // RNE (finite inputs only)
    return (unsigned short)(r >> 16);
}
__device__ __forceinline__ float b2f(unsigned short u) {
    union { unsigned u; float f; } v; v.u = ((unsigned)u) << 16;
    return v.f;
}

// ---------------- prep: fold W1, transpose/convert W2 ----------------
__global__ void prep_kernel(const float* __restrict__ W1,
                            const float* __restrict__ W2,
                            float* __restrict__ ws) {
    int i = blockIdx.x * 256 + threadIdx.x;          // 0..5119
    if (i < H1 * H) {
        int f = i / H, h = i % H;
        // din = [q, k, q-k, q*k]; W1 rows: [0:64)q [64:128)k [128:192)q-k [192:256)q*k
        ws[WS_WKT + i] = W1[(64 + h) * H1 + f] - W1[(128 + h) * H1 + f];
        ws[WS_WPT + i] = W1[(192 + h) * H1 + f];
        ws[WS_WQ + h * H1 + f] = W1[h * H1 + f] + W1[(128 + h) * H1 + f];
    }
    if (i < 48 * SB2_STRIDE) {                       // 4992 bf16 elems
        int n = i / SB2_STRIDE, k = i % SB2_STRIDE;
        float v = (n < H2 && k < H1) ? W2[k * H2 + n] : 0.f;
        ((unsigned short*)(ws + WS_W2T))[i] = f2b(v);
    }
}

// ---------------- main: one block (512 thr) per batch row ----------------
__global__ __launch_bounds__(512, 6)
void din_attn_kernel(const float* __restrict__ query,
                     const float* __restrict__ keys,
                     const int*   __restrict__ keys_length,
                     const float* __restrict__ b1,
                     const float* __restrict__ b2,
                     const float* __restrict__ Wfc,
                     const float* __restrict__ bfc,
                     const float* __restrict__ ws,
                     float* __restrict__ out)
{
    // sA: swizzled bf16 keys [208 rows x 64 cols, 128B rows]; after the
    // af-hoist barrier the same 26624B become 8 per-wave hid scratch bufs.
    __shared__ unsigned short sA[TPAD * 64];     // 26624 B
    __shared__ unsigned short sB1[H1 * 64];      // 10240 B swizzled; sOut aliases later
    __shared__ float sQh[H1];                    //   320 B
    __shared__ float sS[TPAD];                   //   832 B
    __shared__ float sRed[16];                   //    64 B

    const int b   = blockIdx.x;
    const int tid = threadIdx.x;
    const int wv  = tid >> 6, ln = tid & 63;
    const int lrow = ln & 15;             // m/n index within a 16-tile
    const int lk8  = (ln >> 4) * 8;       // k-element offset of this lane's frag
    const int sw   = (lrow & 7) << 3;     // frag-read swizzle (row&7 == lrow&7)

    const float* kb = keys + (size_t)b * T * H;
    const float* qg = query + (size_t)b * H;
    const unsigned short* w2t = (const unsigned short*)(ws + WS_W2T);

    // ---- hoisted small loads ----
    float wfcv[3], b2v[3];
    #pragma unroll
    for (int nt = 0; nt < 3; ++nt) {
        int g = nt * 16 + lrow;
        wfcv[nt] = (g < H2) ? Wfc[g] : 0.f;
        b2v[nt]  = (g < H2) ? b2[g]  : 0.f;
    }
    float bfc0 = bfc[0];
    int len = keys_length[b];

    // ===== phase 0: stage keys (6-7 loads in flight), fold W1, qh =====
    const float4* kb4 = reinterpret_cast<const float4*>(kb);
    float4 kv[6];
    #pragma unroll
    for (int k = 0; k < 6; ++k) kv[k] = kb4[tid + (k << 9)];
    const bool tail = tid < (T * H / 4 - 3072);     // 128 threads
    float4 kvt;
    if (tail) kvt = kb4[tid + 3072];

    #pragma unroll
    for (int k = 0; k < 6; ++k) {
        int idx = tid + (k << 9);
        int t = idx >> 4, h = (idx & 15) << 2;
        uint2 p;
        p.x = (unsigned)f2b(kv[k].x) | ((unsigned)f2b(kv[k].y) << 16);
        p.y = (unsigned)f2b(kv[k].z) | ((unsigned)f2b(kv[k].w) << 16);
        *reinterpret_cast<uint2*>(&sA[t * 64 + (h ^ ((t & 7) << 3))]) = p;
    }
    if (tail) {
        int idx = tid + 3072;
        int t = idx >> 4, h = (idx & 15) << 2;
        uint2 p;
        p.x = (unsigned)f2b(kvt.x) | ((unsigned)f2b(kvt.y) << 16);
        p.y = (unsigned)f2b(kvt.z) | ((unsigned)f2b(kvt.w) << 16);
        *reinterpret_cast<uint2*>(&sA[t * 64 + (h ^ ((t & 7) << 3))]) = p;
    }
    if (tid < 64) {                                  // zero pad rows 200..207
        uint4 z; z.x = z.y = z.z = z.w = 0;
        reinterpret_cast<uint4*>(&sA[200 * 64])[tid] = z;
    }
    // fold q into stage-1 weights: B1[f][h] = Wk[f][h] + q[h]*Wp[f][h]
    #pragma unroll
    for (int k = 0; k < 5; ++k) {
        int idx = tid + (k << 9);                    // 0..2559
        int f = idx >> 5, hp = (idx & 31) << 1;
        float q0 = qg[hp], q1 = qg[hp + 1];
        float v0 = ws[WS_WKT + f * H + hp]     + q0 * ws[WS_WPT + f * H + hp];
        float v1 = ws[WS_WKT + f * H + hp + 1] + q1 * ws[WS_WPT + f * H + hp + 1];
        unsigned p = (unsigned)f2b(v0) | ((unsigned)f2b(v1) << 16);
        *reinterpret_cast<unsigned*>(&sB1[f * 64 + (hp ^ ((f & 7) << 3))]) = p;
    }
    if (tid < H1) {
        float acc = b1[tid];
        #pragma unroll 8
        for (int h = 0; h < H; ++h) acc += qg[h] * ws[WS_WQ + h * H1 + tid];
        sQh[tid] = acc;
    }
    __syncthreads();

    // ===== phase 0.5: hoist key A-fragments, then keys-LDS is dead =====
    short8 af[2][2];
    bool has[2];
    #pragma unroll
    for (int mi = 0; mi < 2; ++mi) {
        int mt = wv + mi * 8;
        has[mi] = (mt < MT);
        if (has[mi]) {
            #pragma unroll
            for (int ks = 0; ks < 2; ++ks) {
                int row = mt * 16 + lrow;
                af[mi][ks] = *reinterpret_cast<const short8*>(
                    &sA[row * 64 + ((ks * 32 + lk8) ^ sw)]);
            }
        }
    }
    __syncthreads();   // all af reads complete before scratch overwrites sA

    // per-wave hid scratch inside sA; zero cols 80..95 (K=96 zero-pad)
    unsigned short* scr = &sA[wv * 16 * SCR_STRIDE];
    {
        uint2 z; z.x = 0; z.y = 0;
        *reinterpret_cast<uint2*>(&scr[(ln >> 2) * SCR_STRIDE + 80 + (ln & 3) * 4]) = z;
    }

    // ===== phase 1: per-M-tile stage1 MFMA -> scratch -> stage2 MFMA =====
    #pragma unroll
    for (int mi = 0; mi < 2; ++mi) {
        if (!has[mi]) break;
        int mt = wv + mi * 8;
        // stage-1: hid[16][80] = ReLU(A @ B1 + qh); B1 streamed from LDS
        #pragma unroll
        for (int nt = 0; nt < 5; ++nt) {
            int row = nt * 16 + lrow;
            short8 bf0 = *reinterpret_cast<const short8*>(&sB1[row * 64 + (lk8 ^ sw)]);
            short8 bf1 = *reinterpret_cast<const short8*>(&sB1[row * 64 + ((32 + lk8) ^ sw)]);
            floatx4 acc = {0.f, 0.f, 0.f, 0.f};
            acc = __builtin_amdgcn_mfma_f32_16x16x32_bf16(af[mi][0], bf0, acc, 0, 0, 0);
            acc = __builtin_amdgcn_mfma_f32_16x16x32_bf16(af[mi][1], bf1, acc, 0, 0, 0);
            float qh = sQh[nt * 16 + lrow];   // D: col=lane&15 (f), row=(lane>>4)*4+r (t)
            int rb = (ln >> 4) * 4;
            #pragma unroll
            for (int r = 0; r < 4; ++r)
                scr[(rb + r) * SCR_STRIDE + nt * 16 + lrow] = f2b(fmaxf(acc[r] + qh, 0.f));
        }
        // stage-2: scores = relu(hid @ W2 + b2) . Wfc  (own scratch, no barrier)
        short8 a2[3];
        #pragma unroll
        for (int ks = 0; ks < 3; ++ks)
            a2[ks] = *reinterpret_cast<const short8*>(
                &scr[lrow * SCR_STRIDE + ks * 32 + lk8]);
        floatx4 vsum = {0.f, 0.f, 0.f, 0.f};
        #pragma unroll
        for (int nt = 0; nt < 3; ++nt) {
            floatx4 acc = {0.f, 0.f, 0.f, 0.f};
            #pragma unroll
            for (int ks = 0; ks < 3; ++ks) {
                short8 b2frag = *reinterpret_cast<const short8*>(
                    &w2t[(nt * 16 + lrow) * SB2_STRIDE + ks * 32 + lk8]);
                acc = __builtin_amdgcn_mfma_f32_16x16x32_bf16(a2[ks], b2frag, acc, 0, 0, 0);
            }
            #pragma unroll
            for (int r = 0; r < 4; ++r)
                vsum[r] += fmaxf(acc[r] + b2v[nt], 0.f) * wfcv[nt];
        }
        #pragma unroll
        for (int r = 0; r < 4; ++r) {
            vsum[r] += __shfl_xor(vsum[r], 1);
            vsum[r] += __shfl_xor(vsum[r], 2);
            vsum[r] += __shfl_xor(vsum[r], 4);
            vsum[r] += __shfl_xor(vsum[r], 8);
        }
        if (lrow == 0) {
            int tb = mt * 16 + (ln >> 4) * 4;
            #pragma unroll
            for (int r = 0; r < 4; ++r)
                sS[tb + r] = (vsum[r] + bfc0) * 0.125f;
        }
    }
    __syncthreads();

    // ===== phase 2: masked softmax (2 barriers; sS becomes UNNORMALIZED e) =====
    float s = -INFINITY;
    if (tid < TPAD) s = (tid < len) ? sS[tid] : -INFINITY;
    float m = s;
    #pragma unroll
    for (int off = 32; off > 0; off >>= 1) m = fmaxf(m, __shfl_xor(m, off));
    if (ln == 0) sRed[wv] = m;
    __syncthreads();
    float mx = sRed[0];
    #pragma unroll
    for (int i = 1; i < 8; ++i) mx = fmaxf(mx, sRed[i]);
    float e = (tid < TPAD) ? __expf(s - mx) : 0.f;
    if (tid < TPAD) sS[tid] = e;          // own slot: read+write by same tid
    float sum = e;
    #pragma unroll
    for (int off = 32; off > 0; off >>= 1) sum += __shfl_xor(sum, off);
    if (ln == 0) sRed[8 + wv] = sum;
    __syncthreads();                      // covers sS(e) writes + sRed sums
    float denom = sRed[8];
    #pragma unroll
    for (int i = 1; i < 8; ++i) denom += sRed[8 + i];
    float inv = 1.f / denom;

    // ===== phase 3: out[h] = inv * sum_t e[t]*K[t][h] — keys from af REGISTERS =====
    float acc3[2][8];
    #pragma unroll
    for (int ks = 0; ks < 2; ++ks)
        #pragma unroll
        for (int j = 0; j < 8; ++j) acc3[ks][j] = 0.f;
    #pragma unroll
    for (int mi = 0; mi < 2; ++mi) {
        if (!has[mi]) break;
        int mt = wv + mi * 8;
        float ew = sS[mt * 16 + lrow];    // e for this lane's key row (pad rows: 0)
        #pragma unroll
        for (int ks = 0; ks < 2; ++ks)
            #pragma unroll
            for (int j = 0; j < 8; ++j)
                acc3[ks][j] += ew * b2f((unsigned short)af[mi][ks][j]);
    }
    #pragma unroll
    for (int ks = 0; ks < 2; ++ks)
        #pragma unroll
        for (int j = 0; j < 8; ++j) {
            float v = acc3[ks][j];
            v += __shfl_xor(v, 1);
            v += __shfl_xor(v, 2);
            v += __shfl_xor(v, 4);
            v += __shfl_xor(v, 8);
            acc3[ks][j] = v;              // summed over 16 rows of wave's tiles
        }
    float* sOut = reinterpret_cast<float*>(sB1);   // sB1 dead after phase 1
    if (lrow == 0) {                               // lanes 0,16,32,48: h = ks*32+kgrp*8+j
        float* dst = &sOut[wv * 64 + (ln >> 4) * 8];
        #pragma unroll
        for (int ks = 0; ks < 2; ++ks) {
            float4 v0, v1;
            v0.x = acc3[ks][0]; v0.y = acc3[ks][1]; v0.z = acc3[ks][2]; v0.w = acc3[ks][3];
            v1.x = acc3[ks][4]; v1.y = acc3[ks][5]; v1.z = acc3[ks][6]; v1.w = acc3[ks][7];
            *reinterpret_cast<float4*>(&dst[ks * 32])     = v0;
            *reinterpret_cast<float4*>(&dst[ks * 32 + 4]) = v1;
        }
    }
    __syncthreads();
    if (tid < H) {
        float o = 0.f;
        #pragma unroll
        for (int g = 0; g < 8; ++g) o += sOut[g * 64 + tid];
        out[(size_t)b * H + tid] = o * inv;
    }
}

extern "C" void kernel_launch(void* const* d_in, const int* in_sizes, int n_in,
                              void* d_out, int out_size, void* d_ws, size_t ws_size,
                              hipStream_t stream) {
    const float* query       = (const float*)d_in[0];
    const float* keys        = (const float*)d_in[1];
    const int*   keys_length = (const int*)  d_in[2];
    const float* W1          = (const float*)d_in[3];
    const float* b1          = (const float*)d_in[4];
    const float* W2          = (const float*)d_in[5];
    const float* b2          = (const float*)d_in[6];
    const float* Wfc         = (const float*)d_in[7];
    const float* bfc         = (const float*)d_in[8];
    float* out = (float*)d_out;
    float* ws  = (float*)d_ws;

    prep_kernel<<<20, 256, 0, stream>>>(W1, W2, ws);
    din_attn_kernel<<<BB, 512, 0, stream>>>(query, keys, keys_length,
                                            b1, b2, Wfc, bfc, ws, out);
}